// Round 1
// baseline (3966.392 us; speedup 1.0000x reference)
//
#include <hip/hip_runtime.h>
#include <cmath>

#define TPB 256
#define RPB 64  // rows per bucket for the binned CSR build (K = ceil(M/64) buckets)

// ---------------- CSR build ----------------

// histogram of all 3 row arrays into one concatenated counts[3N]
__global__ void hist3_kernel(const int* __restrict__ r0, const int* __restrict__ r1,
                             const int* __restrict__ r2, int E, int N,
                             int* __restrict__ counts) {
  int i = blockIdx.x * TPB + threadIdx.x;
  if (i >= E) return;
  const int* rr = blockIdx.y == 0 ? r0 : blockIdx.y == 1 ? r1 : r2;
  atomicAdd(&counts[rr[i] + blockIdx.y * N], 1);
}

// scan over M counts -> P[0..M] (P[0]=0 after scan3), chunk = 2048/block
__global__ void scan1_kernel(const int* __restrict__ counts, int M,
                             int* __restrict__ P, int* __restrict__ S) {
  __shared__ int lds[TPB];
  int base = blockIdx.x * 2048 + threadIdx.x * 8;
  int v[8];
  int run = 0;
#pragma unroll
  for (int i = 0; i < 8; ++i) {
    int idx = base + i;
    int c = (idx < M) ? counts[idx] : 0;
    run += c;
    v[i] = run;
  }
  lds[threadIdx.x] = run;
  __syncthreads();
  for (int off = 1; off < TPB; off <<= 1) {
    int t = 0;
    if ((int)threadIdx.x >= off) t = lds[threadIdx.x - off];
    __syncthreads();
    if ((int)threadIdx.x >= off) lds[threadIdx.x] += t;
    __syncthreads();
  }
  int excl = (threadIdx.x > 0) ? lds[threadIdx.x - 1] : 0;
#pragma unroll
  for (int i = 0; i < 8; ++i) {
    int idx = base + i;
    if (idx < M) P[idx + 1] = v[i] + excl;
  }
  if (threadIdx.x == TPB - 1) S[blockIdx.x] = lds[TPB - 1];
}

__global__ void scan2_kernel(int* __restrict__ S, int NB) {
  __shared__ int lds[TPB];
  int carry = 0;
  for (int b0 = 0; b0 < NB; b0 += TPB) {
    int i = b0 + threadIdx.x;
    int val = (i < NB) ? S[i] : 0;
    lds[threadIdx.x] = val;
    __syncthreads();
    for (int off = 1; off < TPB; off <<= 1) {
      int t = 0;
      if ((int)threadIdx.x >= off) t = lds[threadIdx.x - off];
      __syncthreads();
      if ((int)threadIdx.x >= off) lds[threadIdx.x] += t;
      __syncthreads();
    }
    int inc = lds[threadIdx.x];
    int tot = lds[TPB - 1];
    if (i < NB) S[i] = inc + carry;
    carry += tot;
    __syncthreads();
  }
}

__global__ void scan3_kernel(int* __restrict__ P, const int* __restrict__ S, int M) {
  int b = blockIdx.x;
  int add = (b == 0) ? 0 : S[b - 1];
  int base = b * 2048;
  for (int i = threadIdx.x; i < 2048; i += TPB) {
    int idx = base + i;
    if (idx < M) P[idx + 1] += add;
  }
  if (b == 0 && threadIdx.x == 0) P[0] = 0;
}

// bucket cursor init: bucket b starts at P[b*RPB] (exact capacity by construction)
__global__ void bucket_init_kernel(const int* __restrict__ P, int* __restrict__ bcur, int K) {
  int b = blockIdx.x * TPB + threadIdx.x;
  if (b < K) bcur[b] = P[b * RPB];
}

// phase 1: append (col,val)+row into bucket regions. Appends to ~4688 cursors
// form a dense monotone write frontier (~600 KB of active lines) that stays
// L2-resident -> each 64B line absorbs all its 8B/4B writes and evicts once.
__global__ void binscatter_kernel(const int* __restrict__ r0, const int* __restrict__ c0,
                                  const float* __restrict__ v0,
                                  const int* __restrict__ r1, const int* __restrict__ c1,
                                  const float* __restrict__ v1,
                                  const int* __restrict__ r2, const int* __restrict__ c2,
                                  const float* __restrict__ v2,
                                  int E, int N, int* __restrict__ bcur,
                                  int2* __restrict__ tcv, int* __restrict__ trow) {
  int i = blockIdx.x * TPB + threadIdx.x;
  if (i >= E) return;
  int m = blockIdx.y;
  const int* rr = m == 0 ? r0 : m == 1 ? r1 : r2;
  const int* cc = m == 0 ? c0 : m == 1 ? c1 : c2;
  const float* vv = m == 0 ? v0 : m == 1 ? v1 : v2;
  int r = rr[i] + m * N;
  int pos = atomicAdd(&bcur[r >> 6], 1);  // RPB == 64
  tcv[pos] = make_int2(cc[i], __float_as_int(vv[i]));
  trow[pos] = r;
}

// phase 2: one block per bucket; LDS cursors for the bucket's 64 rows; scatter
// into final CSR positions. Random writes confined to a ~16 KB window ->
// window lines stay in L2 and each absorbs its 8 stores before evicting.
__global__ __launch_bounds__(TPB) void csr_place_kernel(
    const int* __restrict__ P, const int2* __restrict__ tcv,
    const int* __restrict__ trow, int2* __restrict__ pairs, int M) {
  __shared__ int lcur[RPB];
  int row0 = blockIdx.x * RPB;
  int row1 = row0 + RPB;
  if (row1 > M) row1 = M;
  if (threadIdx.x < RPB) {
    int r = row0 + threadIdx.x;
    lcur[threadIdx.x] = (r < M) ? P[r] : 0;
  }
  __syncthreads();
  int start = P[row0], end = P[row1];
  for (int j = start + threadIdx.x; j < end; j += TPB) {
    int r = trow[j];
    int pos = atomicAdd(&lcur[r - row0], 1);
    pairs[pos] = tcv[j];
  }
}

// ---------------- dense GEMM: C[nrows,128] = A @ W (+bias) ----------------
// block 256 thr, tile 128 rows x 128 cols, thread 8x8.
// W staged in 32 KB LDS chunks (k-depth 64).
// Column split {cg*4, 64+cg*4}: 16 lanes sweep all 32 banks -> 2-way LDS
// aliasing (free per m136).
// NOTE (R2 post-mortem): do NOT unroll the k4 loop — unrolling hoists 8
// iterations of a[8] float4 A-loads, VGPR 256 + 1.1 GB spill traffic.

__global__ __launch_bounds__(TPB) void gemm128_kernel(
    const float* __restrict__ A, const float* __restrict__ W,
    const float* __restrict__ bias, float* __restrict__ C, int nrows) {
  __shared__ float sW[64 * 128];
  const int cg = threadIdx.x & 15;
  const int rg = threadIdx.x >> 4;
  const int cA = cg * 4, cB = 64 + cg * 4;
  const int row0 = blockIdx.x * 128 + rg * 8;
  float acc[8][8];
#pragma unroll
  for (int j = 0; j < 8; ++j)
#pragma unroll
    for (int i = 0; i < 8; ++i) acc[j][i] = 0.f;

#pragma unroll 1
  for (int kc = 0; kc < 128; kc += 64) {
    for (int i = threadIdx.x * 4; i < 64 * 128; i += TPB * 4)
      *(float4*)&sW[i] = *(const float4*)&W[kc * 128 + i];
    __syncthreads();
#pragma unroll 1
    for (int k4 = 0; k4 < 64; k4 += 4) {
      float4 a[8];
#pragma unroll
      for (int j = 0; j < 8; ++j) {
        int r = row0 + j;
        a[j] = (r < nrows) ? *(const float4*)&A[(size_t)r * 128 + kc + k4]
                           : make_float4(0.f, 0.f, 0.f, 0.f);
      }
#pragma unroll
      for (int kk = 0; kk < 4; ++kk) {
        float4 w0 = *(const float4*)&sW[(k4 + kk) * 128 + cA];
        float4 w1 = *(const float4*)&sW[(k4 + kk) * 128 + cB];
#pragma unroll
        for (int j = 0; j < 8; ++j) {
          float aj = (kk == 0) ? a[j].x : (kk == 1) ? a[j].y : (kk == 2) ? a[j].z : a[j].w;
          acc[j][0] = fmaf(aj, w0.x, acc[j][0]);
          acc[j][1] = fmaf(aj, w0.y, acc[j][1]);
          acc[j][2] = fmaf(aj, w0.z, acc[j][2]);
          acc[j][3] = fmaf(aj, w0.w, acc[j][3]);
          acc[j][4] = fmaf(aj, w1.x, acc[j][4]);
          acc[j][5] = fmaf(aj, w1.y, acc[j][5]);
          acc[j][6] = fmaf(aj, w1.z, acc[j][6]);
          acc[j][7] = fmaf(aj, w1.w, acc[j][7]);
        }
      }
    }
    __syncthreads();
  }
  float bv[8];
  if (bias) {
    *(float4*)&bv[0] = *(const float4*)&bias[cA];
    *(float4*)&bv[4] = *(const float4*)&bias[cB];
  } else {
#pragma unroll
    for (int i = 0; i < 8; ++i) bv[i] = 0.f;
  }
#pragma unroll
  for (int j = 0; j < 8; ++j) {
    int r = row0 + j;
    if (r < nrows) {
      *(float4*)&C[(size_t)r * 128 + cA] =
          make_float4(acc[j][0] + bv[0], acc[j][1] + bv[1], acc[j][2] + bv[2], acc[j][3] + bv[3]);
      *(float4*)&C[(size_t)r * 128 + cB] =
          make_float4(acc[j][4] + bv[4], acc[j][5] + bv[5], acc[j][6] + bv[6], acc[j][7] + bv[7]);
    }
  }
}

// ---------------- fusion: score[v][n] = w2 . tanh(x[v,n,:] @ W1 + b1) ----------------

__global__ __launch_bounds__(TPB) void fusion_score_kernel(
    const float* __restrict__ x, const float* __restrict__ W1,
    const float* __restrict__ b1, const float* __restrict__ w2,
    float* __restrict__ score, int nrows) {
  __shared__ float sW[64 * 128];
  const int v = blockIdx.y;
  const float* A = x + (size_t)v * nrows * 128;
  const int cg = threadIdx.x & 15;
  const int rg = threadIdx.x >> 4;
  const int cA = cg * 4, cB = 64 + cg * 4;
  const int row0 = blockIdx.x * 128 + rg * 8;
  float acc[8][8];
#pragma unroll
  for (int j = 0; j < 8; ++j)
#pragma unroll
    for (int i = 0; i < 8; ++i) acc[j][i] = 0.f;

#pragma unroll 1
  for (int kc = 0; kc < 128; kc += 64) {
    for (int i = threadIdx.x * 4; i < 64 * 128; i += TPB * 4)
      *(float4*)&sW[i] = *(const float4*)&W1[kc * 128 + i];
    __syncthreads();
#pragma unroll 1
    for (int k4 = 0; k4 < 64; k4 += 4) {
      float4 a[8];
#pragma unroll
      for (int j = 0; j < 8; ++j) {
        int r = row0 + j;
        a[j] = (r < nrows) ? *(const float4*)&A[(size_t)r * 128 + kc + k4]
                           : make_float4(0.f, 0.f, 0.f, 0.f);
      }
#pragma unroll
      for (int kk = 0; kk < 4; ++kk) {
        float4 w0 = *(const float4*)&sW[(k4 + kk) * 128 + cA];
        float4 w1 = *(const float4*)&sW[(k4 + kk) * 128 + cB];
#pragma unroll
        for (int j = 0; j < 8; ++j) {
          float aj = (kk == 0) ? a[j].x : (kk == 1) ? a[j].y : (kk == 2) ? a[j].z : a[j].w;
          acc[j][0] = fmaf(aj, w0.x, acc[j][0]);
          acc[j][1] = fmaf(aj, w0.y, acc[j][1]);
          acc[j][2] = fmaf(aj, w0.z, acc[j][2]);
          acc[j][3] = fmaf(aj, w0.w, acc[j][3]);
          acc[j][4] = fmaf(aj, w1.x, acc[j][4]);
          acc[j][5] = fmaf(aj, w1.y, acc[j][5]);
          acc[j][6] = fmaf(aj, w1.z, acc[j][6]);
          acc[j][7] = fmaf(aj, w1.w, acc[j][7]);
        }
      }
    }
    __syncthreads();
  }
  float bb[8], ww[8];
  *(float4*)&bb[0] = *(const float4*)&b1[cA];
  *(float4*)&bb[4] = *(const float4*)&b1[cB];
  *(float4*)&ww[0] = *(const float4*)&w2[cA];
  *(float4*)&ww[4] = *(const float4*)&w2[cB];
#pragma unroll
  for (int j = 0; j < 8; ++j) {
    float p = 0.f;
#pragma unroll
    for (int i = 0; i < 8; ++i) p += tanhf(acc[j][i] + bb[i]) * ww[i];
#pragma unroll
    for (int off = 8; off > 0; off >>= 1) p += __shfl_down(p, off, 16);
    if (cg == 0 && row0 + j < nrows) score[(size_t)v * nrows + row0 + j] = p;
  }
}

// softmax over 2 views + weighted sum (b2 cancels in the 2-way softmax)
__global__ void combine_kernel(const float* __restrict__ x, const float* __restrict__ score,
                               float* __restrict__ fused, int nrows) {
  int i = blockIdx.x * TPB + threadIdx.x;  // over nrows*32 float4s
  if (i >= nrows * 32) return;
  int n = i >> 5;
  float s0 = score[n], s1 = score[nrows + n];
  float m = fmaxf(s0, s1);
  float e0 = expf(s0 - m), e1 = expf(s1 - m);
  float inv = 1.f / (e0 + e1);
  float w0 = e0 * inv, w1 = e1 * inv;
  float4 a = ((const float4*)x)[i];
  float4 b = ((const float4*)x)[(size_t)nrows * 32 + i];
  ((float4*)fused)[i] = make_float4(w0 * a.x + w1 * b.x, w0 * a.y + w1 * b.y,
                                    w0 * a.z + w1 * b.z, w0 * a.w + w1 * b.w);
}

// ---------------- spmm: y[r,:] = (relu?) sum val * x[col,:] (+add0 +add1) ----------------
// one 32-lane half-wave per row; lanes hold float4 (128 cols / 32 lanes).

__global__ __launch_bounds__(TPB) void spmm_kernel(
    const int* __restrict__ ptr, const int2* __restrict__ pairs,
    const float* __restrict__ x, float* __restrict__ y, int nrows, int do_relu,
    const float* __restrict__ add0, const float* __restrict__ add1) {
  int row = (blockIdx.x * TPB + threadIdx.x) >> 5;
  int hl = threadIdx.x & 31;
  if (row >= nrows) return;
  int start = ptr[row], end = ptr[row + 1];
  float ax = 0.f, ay = 0.f, az = 0.f, aw = 0.f;
  for (int j = start; j < end; j += 32) {
    int nrem = end - j;
    if (nrem > 32) nrem = 32;
    int2 pr = make_int2(0, 0);
    if (hl < nrem) pr = pairs[j + hl];
    for (int t = 0; t < nrem; ++t) {
      int c = __shfl(pr.x, t, 32);
      float v = __int_as_float(__shfl(pr.y, t, 32));
      const float4 xv = *(const float4*)&x[(size_t)c * 128 + hl * 4];
      ax = fmaf(v, xv.x, ax);
      ay = fmaf(v, xv.y, ay);
      az = fmaf(v, xv.z, az);
      aw = fmaf(v, xv.w, aw);
    }
  }
  if (do_relu) {
    ax = fmaxf(ax, 0.f); ay = fmaxf(ay, 0.f);
    az = fmaxf(az, 0.f); aw = fmaxf(aw, 0.f);
  }
  size_t o = (size_t)row * 128 + hl * 4;
  if (add0) { float4 t = *(const float4*)&add0[o]; ax += t.x; ay += t.y; az += t.z; aw += t.w; }
  if (add1) { float4 t = *(const float4*)&add1[o]; ax += t.x; ay += t.y; az += t.z; aw += t.w; }
  *(float4*)&y[o] = make_float4(ax, ay, az, aw);
}

// ---------------- launch ----------------

extern "C" void kernel_launch(void* const* d_in, const int* in_sizes, int n_in,
                              void* d_out, int out_size, void* d_ws, size_t ws_size,
                              hipStream_t stream) {
  const float* x   = (const float*)d_in[0];
  const float* fw1 = (const float*)d_in[1];
  const float* fb1 = (const float*)d_in[2];
  const float* fw2 = (const float*)d_in[3];
  // d_in[4] = fusion_b2: cancels in 2-way softmax
  const float* hgw = (const float*)d_in[5];
  const float* lgw = (const float*)d_in[6];
  const float* lgb = (const float*)d_in[7];
  const float* c1v = (const float*)d_in[8];
  const float* c2v = (const float*)d_in[9];
  const float* lgv = (const float*)d_in[10];
  const int* c1r = (const int*)d_in[11];
  const int* c1c = (const int*)d_in[12];
  const int* c2r = (const int*)d_in[13];
  const int* c2c = (const int*)d_in[14];
  const int* lgr = (const int*)d_in[15];
  const int* lgc = (const int*)d_in[16];

  const int N = in_sizes[0] / 256;  // x is [2,N,128]
  const int E = in_sizes[8];
  const int M = 3 * N;
  const int K = (M + RPB - 1) / RPB;

  char* ws = (char*)d_ws;
  size_t off = 0;
  auto alloc = [&](size_t bytes) -> void* {
    void* p = ws + off;
    off += (bytes + 511) & ~(size_t)511;
    return p;
  };
  int* P      = (int*)alloc((size_t)(M + 1) * 4);
  int* S      = (int*)alloc((size_t)4096 * 4);
  int* counts = (int*)alloc((size_t)M * 4);
  int* bcur   = (int*)alloc((size_t)K * 4);
  int2* pairs = (int2*)alloc((size_t)3 * E * 8);
  float* score = (float*)alloc((size_t)2 * N * 4);
  float* Fbase = (float*)alloc((size_t)3 * N * 128 * 4);
  float* F0 = Fbase;
  float* F1 = Fbase + (size_t)N * 128;
  float* F2 = Fbase + (size_t)2 * N * 128;
  // CSR-build temporaries alias the F buffers: the build completes (stream-
  // ordered) before fusion/combine first write F0/F1/F2.
  // tcv: 3E*8 = 76.8 MB, trow: 3E*4 = 38.4 MB  <=  F region 153.6 MB.
  int2* tcv = (int2*)Fbase;
  int* trow = (int*)(tcv + (size_t)3 * E);
  float* outH = (float*)d_out;
  float* outA = (float*)d_out + (size_t)N * 128;

  // ---- CSR build for [coef1 | coef2 | lg] concatenated ----
  hipMemsetAsync(counts, 0, (size_t)M * 4, stream);
  int gE = (E + TPB - 1) / TPB;
  dim3 g3(gE, 3);
  hist3_kernel<<<g3, TPB, 0, stream>>>(c1r, c2r, lgr, E, N, counts);
  int NB = (M + 2047) / 2048;
  scan1_kernel<<<NB, TPB, 0, stream>>>(counts, M, P, S);
  scan2_kernel<<<1, TPB, 0, stream>>>(S, NB);
  scan3_kernel<<<NB, TPB, 0, stream>>>(P, S, M);
  bucket_init_kernel<<<(K + TPB - 1) / TPB, TPB, 0, stream>>>(P, bcur, K);
  binscatter_kernel<<<g3, TPB, 0, stream>>>(c1r, c1c, c1v, c2r, c2c, c2v,
                                            lgr, lgc, lgv, E, N, bcur, tcv, trow);
  csr_place_kernel<<<K, TPB, 0, stream>>>(P, tcv, trow, pairs, M);

  // ---- fusion ----
  dim3 gf((N + 127) / 128, 2);
  fusion_score_kernel<<<gf, TPB, 0, stream>>>(x, fw1, fb1, fw2, score, N);
  combine_kernel<<<(N * 32 + TPB - 1) / TPB, TPB, 0, stream>>>(x, score, F0, N);

  int gg = (N + 127) / 128;
  int gs = (N + 7) / 8;  // spmm: 8 half-waves/block, half-wave per row

  // ---- HGCN ----
  gemm128_kernel<<<gg, TPB, 0, stream>>>(F0, hgw + 0 * 16384, nullptr, F1, N);
  spmm_kernel<<<gs, TPB, 0, stream>>>(P, pairs, F1, F2, N, 1, nullptr, nullptr);      // h1
  gemm128_kernel<<<gg, TPB, 0, stream>>>(F2, hgw + 1 * 16384, nullptr, F1, N);
  spmm_kernel<<<gs, TPB, 0, stream>>>(P, pairs, F1, F2, N, 1, nullptr, nullptr);      // h2
  gemm128_kernel<<<gg, TPB, 0, stream>>>(F2, hgw + 2 * 16384, nullptr, F1, N);
  spmm_kernel<<<gs, TPB, 0, stream>>>(P, pairs, F1, outH, N, 1, nullptr, nullptr);    // h3 -> out[0:N]
  spmm_kernel<<<gs, TPB, 0, stream>>>(P + N, pairs, outH, F0, N, 1, nullptr, nullptr); // y

  // ---- LineConv ----
  gemm128_kernel<<<gg, TPB, 0, stream>>>(F0, lgw + 0 * 16384, lgb + 0, F1, N);
  spmm_kernel<<<gs, TPB, 0, stream>>>(P + 2 * N, pairs, F1, F2, N, 0, nullptr, nullptr); // cur1
  gemm128_kernel<<<gg, TPB, 0, stream>>>(F2, lgw + 1 * 16384, lgb + 128, F1, N);
  // cur2 + y + cur1 -> out[N:2N]
  spmm_kernel<<<gs, TPB, 0, stream>>>(P + 2 * N, pairs, F1, outA, N, 0, F0, F2);
}

// Round 2
// 3965.498 us; speedup vs baseline: 1.0002x; 1.0002x over previous
//
#include <hip/hip_runtime.h>
#include <cmath>

#define TPB 256
#define RPB 64   // rows per bucket for the binned CSR build (K = ceil(M/64) buckets)
#define GRP 64   // privatization groups: g = blockIdx&63 -> one XCD per group (round-robin heuristic)

// ---------------- CSR build ----------------
// R1 post-mortem: a single shared bucket frontier gets stores from all 8 XCDs;
// private per-XCD L2s each evict partial copies of every frontier line -> 6x
// write amplification (697 MB measured), plus ~2048-deep same-address atomic
// serialization. Fix: 64-way group privatization keyed off blockIdx&63 so each
// (group,bucket) run (~384 B) is written by one XCD, and counters see only ~32
// atomics each.

// fused: row-level histogram (for P) + (bucket,group) histogram (for P2)
__global__ void hist_count_kernel(const int* __restrict__ r0, const int* __restrict__ r1,
                                  const int* __restrict__ r2, int E, int N,
                                  int* __restrict__ counts, int* __restrict__ Cb) {
  int t = blockIdx.x * TPB + threadIdx.x;
  if (t >= 3 * E) return;
  int g = blockIdx.x & (GRP - 1);
  int m = (t >= 2 * E) ? 2 : (t >= E) ? 1 : 0;
  int i = t - m * E;
  const int* rr = m == 0 ? r0 : m == 1 ? r1 : r2;
  int gr = rr[i] + m * N;
  atomicAdd(&counts[gr], 1);
  atomicAdd(&Cb[(gr >> 6) * GRP + g], 1);
}

// scan over M counts -> P[0..M] (P[0]=0 after scan3), chunk = 2048/block
__global__ void scan1_kernel(const int* __restrict__ counts, int M,
                             int* __restrict__ P, int* __restrict__ S) {
  __shared__ int lds[TPB];
  int base = blockIdx.x * 2048 + threadIdx.x * 8;
  int v[8];
  int run = 0;
#pragma unroll
  for (int i = 0; i < 8; ++i) {
    int idx = base + i;
    int c = (idx < M) ? counts[idx] : 0;
    run += c;
    v[i] = run;
  }
  lds[threadIdx.x] = run;
  __syncthreads();
  for (int off = 1; off < TPB; off <<= 1) {
    int t = 0;
    if ((int)threadIdx.x >= off) t = lds[threadIdx.x - off];
    __syncthreads();
    if ((int)threadIdx.x >= off) lds[threadIdx.x] += t;
    __syncthreads();
  }
  int excl = (threadIdx.x > 0) ? lds[threadIdx.x - 1] : 0;
#pragma unroll
  for (int i = 0; i < 8; ++i) {
    int idx = base + i;
    if (idx < M) P[idx + 1] = v[i] + excl;
  }
  if (threadIdx.x == TPB - 1) S[blockIdx.x] = lds[TPB - 1];
}

__global__ void scan2_kernel(int* __restrict__ S, int NB) {
  __shared__ int lds[TPB];
  int carry = 0;
  for (int b0 = 0; b0 < NB; b0 += TPB) {
    int i = b0 + threadIdx.x;
    int val = (i < NB) ? S[i] : 0;
    lds[threadIdx.x] = val;
    __syncthreads();
    for (int off = 1; off < TPB; off <<= 1) {
      int t = 0;
      if ((int)threadIdx.x >= off) t = lds[threadIdx.x - off];
      __syncthreads();
      if ((int)threadIdx.x >= off) lds[threadIdx.x] += t;
      __syncthreads();
    }
    int inc = lds[threadIdx.x];
    int tot = lds[TPB - 1];
    if (i < NB) S[i] = inc + carry;
    carry += tot;
    __syncthreads();
  }
}

__global__ void scan3_kernel(int* __restrict__ P, const int* __restrict__ S, int M) {
  int b = blockIdx.x;
  int add = (b == 0) ? 0 : S[b - 1];
  int base = b * 2048;
  for (int i = threadIdx.x; i < 2048; i += TPB) {
    int idx = base + i;
    if (idx < M) P[idx + 1] += add;
  }
  if (b == 0 && threadIdx.x == 0) P[0] = 0;
}

// phase 1: append (col,val)+row into per-(bucket,group) runs. The scanned P2
// array doubles as the cursor array (it is scratch after the scan). Same
// grid/indexing as hist_count so each edge lands in the group it was counted in.
__global__ void passB_kernel(const int* __restrict__ r0, const int* __restrict__ c0,
                             const float* __restrict__ v0,
                             const int* __restrict__ r1, const int* __restrict__ c1,
                             const float* __restrict__ v1,
                             const int* __restrict__ r2, const int* __restrict__ c2,
                             const float* __restrict__ v2,
                             int E, int N, int* __restrict__ cur,
                             int2* __restrict__ tcv, int* __restrict__ trow) {
  int t = blockIdx.x * TPB + threadIdx.x;
  if (t >= 3 * E) return;
  int g = blockIdx.x & (GRP - 1);
  int m = (t >= 2 * E) ? 2 : (t >= E) ? 1 : 0;
  int i = t - m * E;
  const int* rr = m == 0 ? r0 : m == 1 ? r1 : r2;
  const int* cc = m == 0 ? c0 : m == 1 ? c1 : c2;
  const float* vv = m == 0 ? v0 : m == 1 ? v1 : v2;
  int gr = rr[i] + m * N;
  int pos = atomicAdd(&cur[(gr >> 6) * GRP + g], 1);
  tcv[pos] = make_int2(cc[i], __float_as_int(vv[i]));
  trow[pos] = gr;
}

// phase 2: one block per bucket; LDS cursors for the bucket's 64 rows; scatter
// into final CSR positions. Random writes confined to a ~16 KB window ->
// window lines stay in (one XCD's) L2 and absorb their stores.
__global__ __launch_bounds__(TPB) void csr_place_kernel(
    const int* __restrict__ P, const int2* __restrict__ tcv,
    const int* __restrict__ trow, int2* __restrict__ pairs, int M) {
  __shared__ int lcur[RPB];
  int row0 = blockIdx.x * RPB;
  int row1 = row0 + RPB;
  if (row1 > M) row1 = M;
  if (threadIdx.x < RPB) {
    int r = row0 + threadIdx.x;
    lcur[threadIdx.x] = (r < M) ? P[r] : 0;
  }
  __syncthreads();
  int start = P[row0], end = P[row1];
  for (int j = start + threadIdx.x; j < end; j += TPB) {
    int r = trow[j];
    int pos = atomicAdd(&lcur[r - row0], 1);
    pairs[pos] = tcv[j];
  }
}

// ---------------- dense GEMM: C[nrows,128] = A @ W (+bias) ----------------
// block 256 thr, tile 128 rows x 128 cols, thread 8x8.
// W staged in 32 KB LDS chunks (k-depth 64).
// Column split {cg*4, 64+cg*4}: 16 lanes sweep all 32 banks -> 2-way LDS
// aliasing (free per m136).
// NOTE (R2 post-mortem): do NOT unroll the k4 loop — unrolling hoists 8
// iterations of a[8] float4 A-loads, VGPR 256 + 1.1 GB spill traffic.

__global__ __launch_bounds__(TPB) void gemm128_kernel(
    const float* __restrict__ A, const float* __restrict__ W,
    const float* __restrict__ bias, float* __restrict__ C, int nrows) {
  __shared__ float sW[64 * 128];
  const int cg = threadIdx.x & 15;
  const int rg = threadIdx.x >> 4;
  const int cA = cg * 4, cB = 64 + cg * 4;
  const int row0 = blockIdx.x * 128 + rg * 8;
  float acc[8][8];
#pragma unroll
  for (int j = 0; j < 8; ++j)
#pragma unroll
    for (int i = 0; i < 8; ++i) acc[j][i] = 0.f;

#pragma unroll 1
  for (int kc = 0; kc < 128; kc += 64) {
    for (int i = threadIdx.x * 4; i < 64 * 128; i += TPB * 4)
      *(float4*)&sW[i] = *(const float4*)&W[kc * 128 + i];
    __syncthreads();
#pragma unroll 1
    for (int k4 = 0; k4 < 64; k4 += 4) {
      float4 a[8];
#pragma unroll
      for (int j = 0; j < 8; ++j) {
        int r = row0 + j;
        a[j] = (r < nrows) ? *(const float4*)&A[(size_t)r * 128 + kc + k4]
                           : make_float4(0.f, 0.f, 0.f, 0.f);
      }
#pragma unroll
      for (int kk = 0; kk < 4; ++kk) {
        float4 w0 = *(const float4*)&sW[(k4 + kk) * 128 + cA];
        float4 w1 = *(const float4*)&sW[(k4 + kk) * 128 + cB];
#pragma unroll
        for (int j = 0; j < 8; ++j) {
          float aj = (kk == 0) ? a[j].x : (kk == 1) ? a[j].y : (kk == 2) ? a[j].z : a[j].w;
          acc[j][0] = fmaf(aj, w0.x, acc[j][0]);
          acc[j][1] = fmaf(aj, w0.y, acc[j][1]);
          acc[j][2] = fmaf(aj, w0.z, acc[j][2]);
          acc[j][3] = fmaf(aj, w0.w, acc[j][3]);
          acc[j][4] = fmaf(aj, w1.x, acc[j][4]);
          acc[j][5] = fmaf(aj, w1.y, acc[j][5]);
          acc[j][6] = fmaf(aj, w1.z, acc[j][6]);
          acc[j][7] = fmaf(aj, w1.w, acc[j][7]);
        }
      }
    }
    __syncthreads();
  }
  float bv[8];
  if (bias) {
    *(float4*)&bv[0] = *(const float4*)&bias[cA];
    *(float4*)&bv[4] = *(const float4*)&bias[cB];
  } else {
#pragma unroll
    for (int i = 0; i < 8; ++i) bv[i] = 0.f;
  }
#pragma unroll
  for (int j = 0; j < 8; ++j) {
    int r = row0 + j;
    if (r < nrows) {
      *(float4*)&C[(size_t)r * 128 + cA] =
          make_float4(acc[j][0] + bv[0], acc[j][1] + bv[1], acc[j][2] + bv[2], acc[j][3] + bv[3]);
      *(float4*)&C[(size_t)r * 128 + cB] =
          make_float4(acc[j][4] + bv[4], acc[j][5] + bv[5], acc[j][6] + bv[6], acc[j][7] + bv[7]);
    }
  }
}

// ---------------- fusion: score[v][n] = w2 . tanh(x[v,n,:] @ W1 + b1) ----------------

__global__ __launch_bounds__(TPB) void fusion_score_kernel(
    const float* __restrict__ x, const float* __restrict__ W1,
    const float* __restrict__ b1, const float* __restrict__ w2,
    float* __restrict__ score, int nrows) {
  __shared__ float sW[64 * 128];
  const int v = blockIdx.y;
  const float* A = x + (size_t)v * nrows * 128;
  const int cg = threadIdx.x & 15;
  const int rg = threadIdx.x >> 4;
  const int cA = cg * 4, cB = 64 + cg * 4;
  const int row0 = blockIdx.x * 128 + rg * 8;
  float acc[8][8];
#pragma unroll
  for (int j = 0; j < 8; ++j)
#pragma unroll
    for (int i = 0; i < 8; ++i) acc[j][i] = 0.f;

#pragma unroll 1
  for (int kc = 0; kc < 128; kc += 64) {
    for (int i = threadIdx.x * 4; i < 64 * 128; i += TPB * 4)
      *(float4*)&sW[i] = *(const float4*)&W1[kc * 128 + i];
    __syncthreads();
#pragma unroll 1
    for (int k4 = 0; k4 < 64; k4 += 4) {
      float4 a[8];
#pragma unroll
      for (int j = 0; j < 8; ++j) {
        int r = row0 + j;
        a[j] = (r < nrows) ? *(const float4*)&A[(size_t)r * 128 + kc + k4]
                           : make_float4(0.f, 0.f, 0.f, 0.f);
      }
#pragma unroll
      for (int kk = 0; kk < 4; ++kk) {
        float4 w0 = *(const float4*)&sW[(k4 + kk) * 128 + cA];
        float4 w1 = *(const float4*)&sW[(k4 + kk) * 128 + cB];
#pragma unroll
        for (int j = 0; j < 8; ++j) {
          float aj = (kk == 0) ? a[j].x : (kk == 1) ? a[j].y : (kk == 2) ? a[j].z : a[j].w;
          acc[j][0] = fmaf(aj, w0.x, acc[j][0]);
          acc[j][1] = fmaf(aj, w0.y, acc[j][1]);
          acc[j][2] = fmaf(aj, w0.z, acc[j][2]);
          acc[j][3] = fmaf(aj, w0.w, acc[j][3]);
          acc[j][4] = fmaf(aj, w1.x, acc[j][4]);
          acc[j][5] = fmaf(aj, w1.y, acc[j][5]);
          acc[j][6] = fmaf(aj, w1.z, acc[j][6]);
          acc[j][7] = fmaf(aj, w1.w, acc[j][7]);
        }
      }
    }
    __syncthreads();
  }
  float bb[8], ww[8];
  *(float4*)&bb[0] = *(const float4*)&b1[cA];
  *(float4*)&bb[4] = *(const float4*)&b1[cB];
  *(float4*)&ww[0] = *(const float4*)&w2[cA];
  *(float4*)&ww[4] = *(const float4*)&w2[cB];
#pragma unroll
  for (int j = 0; j < 8; ++j) {
    float p = 0.f;
#pragma unroll
    for (int i = 0; i < 8; ++i) p += tanhf(acc[j][i] + bb[i]) * ww[i];
#pragma unroll
    for (int off = 8; off > 0; off >>= 1) p += __shfl_down(p, off, 16);
    if (cg == 0 && row0 + j < nrows) score[(size_t)v * nrows + row0 + j] = p;
  }
}

// softmax over 2 views + weighted sum (b2 cancels in the 2-way softmax)
__global__ void combine_kernel(const float* __restrict__ x, const float* __restrict__ score,
                               float* __restrict__ fused, int nrows) {
  int i = blockIdx.x * TPB + threadIdx.x;  // over nrows*32 float4s
  if (i >= nrows * 32) return;
  int n = i >> 5;
  float s0 = score[n], s1 = score[nrows + n];
  float m = fmaxf(s0, s1);
  float e0 = expf(s0 - m), e1 = expf(s1 - m);
  float inv = 1.f / (e0 + e1);
  float w0 = e0 * inv, w1 = e1 * inv;
  float4 a = ((const float4*)x)[i];
  float4 b = ((const float4*)x)[(size_t)nrows * 32 + i];
  ((float4*)fused)[i] = make_float4(w0 * a.x + w1 * b.x, w0 * a.y + w1 * b.y,
                                    w0 * a.z + w1 * b.z, w0 * a.w + w1 * b.w);
}

// ---------------- spmm: y[r,:] = (relu?) sum val * x[col,:] (+add0 +add1) ----------------
// one 32-lane half-wave per row; lanes hold float4 (128 cols / 32 lanes).

__global__ __launch_bounds__(TPB) void spmm_kernel(
    const int* __restrict__ ptr, const int2* __restrict__ pairs,
    const float* __restrict__ x, float* __restrict__ y, int nrows, int do_relu,
    const float* __restrict__ add0, const float* __restrict__ add1) {
  int row = (blockIdx.x * TPB + threadIdx.x) >> 5;
  int hl = threadIdx.x & 31;
  if (row >= nrows) return;
  int start = ptr[row], end = ptr[row + 1];
  float ax = 0.f, ay = 0.f, az = 0.f, aw = 0.f;
  for (int j = start; j < end; j += 32) {
    int nrem = end - j;
    if (nrem > 32) nrem = 32;
    int2 pr = make_int2(0, 0);
    if (hl < nrem) pr = pairs[j + hl];
    for (int t = 0; t < nrem; ++t) {
      int c = __shfl(pr.x, t, 32);
      float v = __int_as_float(__shfl(pr.y, t, 32));
      const float4 xv = *(const float4*)&x[(size_t)c * 128 + hl * 4];
      ax = fmaf(v, xv.x, ax);
      ay = fmaf(v, xv.y, ay);
      az = fmaf(v, xv.z, az);
      aw = fmaf(v, xv.w, aw);
    }
  }
  if (do_relu) {
    ax = fmaxf(ax, 0.f); ay = fmaxf(ay, 0.f);
    az = fmaxf(az, 0.f); aw = fmaxf(aw, 0.f);
  }
  size_t o = (size_t)row * 128 + hl * 4;
  if (add0) { float4 t = *(const float4*)&add0[o]; ax += t.x; ay += t.y; az += t.z; aw += t.w; }
  if (add1) { float4 t = *(const float4*)&add1[o]; ax += t.x; ay += t.y; az += t.z; aw += t.w; }
  *(float4*)&y[o] = make_float4(ax, ay, az, aw);
}

// ---------------- launch ----------------

extern "C" void kernel_launch(void* const* d_in, const int* in_sizes, int n_in,
                              void* d_out, int out_size, void* d_ws, size_t ws_size,
                              hipStream_t stream) {
  const float* x   = (const float*)d_in[0];
  const float* fw1 = (const float*)d_in[1];
  const float* fb1 = (const float*)d_in[2];
  const float* fw2 = (const float*)d_in[3];
  // d_in[4] = fusion_b2: cancels in 2-way softmax
  const float* hgw = (const float*)d_in[5];
  const float* lgw = (const float*)d_in[6];
  const float* lgb = (const float*)d_in[7];
  const float* c1v = (const float*)d_in[8];
  const float* c2v = (const float*)d_in[9];
  const float* lgv = (const float*)d_in[10];
  const int* c1r = (const int*)d_in[11];
  const int* c1c = (const int*)d_in[12];
  const int* c2r = (const int*)d_in[13];
  const int* c2c = (const int*)d_in[14];
  const int* lgr = (const int*)d_in[15];
  const int* lgc = (const int*)d_in[16];

  const int N = in_sizes[0] / 256;  // x is [2,N,128]
  const int E = in_sizes[8];
  const int M = 3 * N;
  const int K = (M + RPB - 1) / RPB;
  const int KG = K * GRP;

  char* ws = (char*)d_ws;
  size_t off = 0;
  auto alloc = [&](size_t bytes) -> void* {
    void* p = ws + off;
    off += (bytes + 511) & ~(size_t)511;
    return p;
  };
  int* P      = (int*)alloc((size_t)(M + 1) * 4);
  int* S      = (int*)alloc((size_t)4096 * 4);
  int* counts = (int*)alloc((size_t)M * 4);
  int* Cb     = (int*)alloc((size_t)KG * 4);
  int* P2     = (int*)alloc((size_t)(KG + 1) * 4);
  int* S2     = (int*)alloc((size_t)4096 * 4);
  int2* pairs = (int2*)alloc((size_t)3 * E * 8);
  float* score = (float*)alloc((size_t)2 * N * 4);
  float* Fbase = (float*)alloc((size_t)3 * N * 128 * 4);
  float* F0 = Fbase;
  float* F1 = Fbase + (size_t)N * 128;
  float* F2 = Fbase + (size_t)2 * N * 128;
  // CSR-build temporaries alias the F buffers: the build completes (stream-
  // ordered) before fusion/combine first write F0/F1/F2.
  // tcv: 3E*8 = 76.8 MB, trow: 3E*4 = 38.4 MB  <=  F region 153.6 MB.
  int2* tcv = (int2*)Fbase;
  int* trow = (int*)(tcv + (size_t)3 * E);
  float* outH = (float*)d_out;
  float* outA = (float*)d_out + (size_t)N * 128;

  // ---- CSR build for [coef1 | coef2 | lg] concatenated ----
  hipMemsetAsync(counts, 0, (size_t)M * 4, stream);
  hipMemsetAsync(Cb, 0, (size_t)KG * 4, stream);
  int NB3 = (3 * E + TPB - 1) / TPB;
  hist_count_kernel<<<NB3, TPB, 0, stream>>>(c1r, c2r, lgr, E, N, counts, Cb);
  int NB = (M + 2047) / 2048;
  scan1_kernel<<<NB, TPB, 0, stream>>>(counts, M, P, S);
  scan2_kernel<<<1, TPB, 0, stream>>>(S, NB);
  scan3_kernel<<<NB, TPB, 0, stream>>>(P, S, M);
  int NB2 = (KG + 2047) / 2048;
  scan1_kernel<<<NB2, TPB, 0, stream>>>(Cb, KG, P2, S2);
  scan2_kernel<<<1, TPB, 0, stream>>>(S2, NB2);
  scan3_kernel<<<NB2, TPB, 0, stream>>>(P2, S2, KG);
  // P2 is now the exclusive offset of each (bucket,group) run; use it as cursors.
  passB_kernel<<<NB3, TPB, 0, stream>>>(c1r, c1c, c1v, c2r, c2c, c2v,
                                        lgr, lgc, lgv, E, N, P2, tcv, trow);
  csr_place_kernel<<<K, TPB, 0, stream>>>(P, tcv, trow, pairs, M);

  // ---- fusion ----
  dim3 gf((N + 127) / 128, 2);
  fusion_score_kernel<<<gf, TPB, 0, stream>>>(x, fw1, fb1, fw2, score, N);
  combine_kernel<<<(N * 32 + TPB - 1) / TPB, TPB, 0, stream>>>(x, score, F0, N);

  int gg = (N + 127) / 128;
  int gs = (N + 7) / 8;  // spmm: 8 half-waves/block, half-wave per row

  // ---- HGCN ----
  gemm128_kernel<<<gg, TPB, 0, stream>>>(F0, hgw + 0 * 16384, nullptr, F1, N);
  spmm_kernel<<<gs, TPB, 0, stream>>>(P, pairs, F1, F2, N, 1, nullptr, nullptr);      // h1
  gemm128_kernel<<<gg, TPB, 0, stream>>>(F2, hgw + 1 * 16384, nullptr, F1, N);
  spmm_kernel<<<gs, TPB, 0, stream>>>(P, pairs, F1, F2, N, 1, nullptr, nullptr);      // h2
  gemm128_kernel<<<gg, TPB, 0, stream>>>(F2, hgw + 2 * 16384, nullptr, F1, N);
  spmm_kernel<<<gs, TPB, 0, stream>>>(P, pairs, F1, outH, N, 1, nullptr, nullptr);    // h3 -> out[0:N]
  spmm_kernel<<<gs, TPB, 0, stream>>>(P + N, pairs, outH, F0, N, 1, nullptr, nullptr); // y

  // ---- LineConv ----
  gemm128_kernel<<<gg, TPB, 0, stream>>>(F0, lgw + 0 * 16384, lgb + 0, F1, N);
  spmm_kernel<<<gs, TPB, 0, stream>>>(P + 2 * N, pairs, F1, F2, N, 0, nullptr, nullptr); // cur1
  gemm128_kernel<<<gg, TPB, 0, stream>>>(F2, lgw + 1 * 16384, lgb + 128, F1, N);
  // cur2 + y + cur1 -> out[N:2N]
  spmm_kernel<<<gs, TPB, 0, stream>>>(P + 2 * N, pairs, F1, outA, N, 0, F0, F2);
}

// Round 3
// 2999.157 us; speedup vs baseline: 1.3225x; 1.3222x over previous
//
#include <hip/hip_runtime.h>
#include <cmath>

#define TPB 256
#define CSH 10               // coarse bucket = 1024 rows
#define CMAX 512             // max coarse buckets supported by LDS hist (M <= 512*1024)
#define CHUNK 16384          // edges per binsort block
#define TPB2 1024            // threads for csr_place2

// ---------------- CSR build ----------------
// R1/R2 post-mortem: scattered single-edge appends (per-row or per-(bucket,
// group)) are write-amplified ~6-7x because each 64B line's 8 writes arrive
// from different blocks spread over the whole kernel duration -- no L2 line
// survives between them, regardless of XCD ownership. Write-combining needs
// TEMPORAL clustering: all writes to a line from one block, back-to-back.
// Fix: block-local counting sort. Each block histograms its 16K-edge chunk by
// coarse bucket (1024 rows), bulk-reserves a contiguous run per bucket with
// ONE global atomic, then streams edges into its runs (~448 B each, written
// within the block's lifetime -> ~1.15x amp). Phase 2 scatters each coarse
// bucket's run-concatenation into final CSR order inside a 262 KB window
// (single block, single XCD, µs-clustered -- the pattern csr_place already
// proved cheap in R1/R2).

// histogram of all 3 row arrays into one concatenated counts[3N]
__global__ void hist3_kernel(const int* __restrict__ r0, const int* __restrict__ r1,
                             const int* __restrict__ r2, int E, int N,
                             int* __restrict__ counts) {
  int i = blockIdx.x * TPB + threadIdx.x;
  if (i >= E) return;
  const int* rr = blockIdx.y == 0 ? r0 : blockIdx.y == 1 ? r1 : r2;
  atomicAdd(&counts[rr[i] + blockIdx.y * N], 1);
}

// scan over M counts -> P[0..M] (P[0]=0 after scan3), chunk = 2048/block
__global__ void scan1_kernel(const int* __restrict__ counts, int M,
                             int* __restrict__ P, int* __restrict__ S) {
  __shared__ int lds[TPB];
  int base = blockIdx.x * 2048 + threadIdx.x * 8;
  int v[8];
  int run = 0;
#pragma unroll
  for (int i = 0; i < 8; ++i) {
    int idx = base + i;
    int c = (idx < M) ? counts[idx] : 0;
    run += c;
    v[i] = run;
  }
  lds[threadIdx.x] = run;
  __syncthreads();
  for (int off = 1; off < TPB; off <<= 1) {
    int t = 0;
    if ((int)threadIdx.x >= off) t = lds[threadIdx.x - off];
    __syncthreads();
    if ((int)threadIdx.x >= off) lds[threadIdx.x] += t;
    __syncthreads();
  }
  int excl = (threadIdx.x > 0) ? lds[threadIdx.x - 1] : 0;
#pragma unroll
  for (int i = 0; i < 8; ++i) {
    int idx = base + i;
    if (idx < M) P[idx + 1] = v[i] + excl;
  }
  if (threadIdx.x == TPB - 1) S[blockIdx.x] = lds[TPB - 1];
}

__global__ void scan2_kernel(int* __restrict__ S, int NB) {
  __shared__ int lds[TPB];
  int carry = 0;
  for (int b0 = 0; b0 < NB; b0 += TPB) {
    int i = b0 + threadIdx.x;
    int val = (i < NB) ? S[i] : 0;
    lds[threadIdx.x] = val;
    __syncthreads();
    for (int off = 1; off < TPB; off <<= 1) {
      int t = 0;
      if ((int)threadIdx.x >= off) t = lds[threadIdx.x - off];
      __syncthreads();
      if ((int)threadIdx.x >= off) lds[threadIdx.x] += t;
      __syncthreads();
    }
    int inc = lds[threadIdx.x];
    int tot = lds[TPB - 1];
    if (i < NB) S[i] = inc + carry;
    carry += tot;
    __syncthreads();
  }
}

__global__ void scan3_kernel(int* __restrict__ P, const int* __restrict__ S, int M) {
  int b = blockIdx.x;
  int add = (b == 0) ? 0 : S[b - 1];
  int base = b * 2048;
  for (int i = threadIdx.x; i < 2048; i += TPB) {
    int idx = base + i;
    if (idx < M) P[idx + 1] += add;
  }
  if (b == 0 && threadIdx.x == 0) P[0] = 0;
}

// coarse-bucket cursor init: region for bucket c = [P[c<<CSH], P[(c+1)<<CSH])
__global__ void ccur_init_kernel(const int* __restrict__ P, int* __restrict__ ccur,
                                 int C, int M) {
  int c = blockIdx.x * TPB + threadIdx.x;
  if (c < C) {
    int r = c << CSH;
    ccur[c] = P[r < M ? r : M];
  }
}

// phase 1: block-local counting sort into coarse-bucket staging runs.
// Record: (col<<CSH | row_low_bits, val) -- 8 B. Requires col < 2^(31-CSH)
// (N=100K << 2^21, ok).
__global__ __launch_bounds__(TPB) void binsort_kernel(
    const int* __restrict__ r0, const int* __restrict__ c0, const float* __restrict__ v0,
    const int* __restrict__ r1, const int* __restrict__ c1, const float* __restrict__ v1,
    const int* __restrict__ r2, const int* __restrict__ c2, const float* __restrict__ v2,
    int E, int N, int C, int* __restrict__ ccur, int2* __restrict__ stage) {
  __shared__ int hist[CMAX];
  int t0 = blockIdx.x * CHUNK;
  int t1 = t0 + CHUNK;
  int tot = 3 * E;
  if (t1 > tot) t1 = tot;
  for (int c = threadIdx.x; c < C; c += TPB) hist[c] = 0;
  __syncthreads();
  // pass A: LDS histogram of this chunk by coarse bucket
  for (int t = t0 + (int)threadIdx.x; t < t1; t += TPB) {
    int m = (t >= 2 * E) ? 2 : (t >= E) ? 1 : 0;
    int i = t - m * E;
    const int* rr = m == 0 ? r0 : m == 1 ? r1 : r2;
    int gr = rr[i] + m * N;
    atomicAdd(&hist[gr >> CSH], 1);
  }
  __syncthreads();
  // bulk reservation: one global atomic per non-empty bucket; hist becomes
  // the block's running cursor per bucket.
  for (int c = threadIdx.x; c < C; c += TPB) {
    int h = hist[c];
    hist[c] = h ? atomicAdd(&ccur[c], h) : 0;
  }
  __syncthreads();
  // pass B: re-read chunk (L2-hot) and stream into reserved runs
  for (int t = t0 + (int)threadIdx.x; t < t1; t += TPB) {
    int m = (t >= 2 * E) ? 2 : (t >= E) ? 1 : 0;
    int i = t - m * E;
    const int* rr = m == 0 ? r0 : m == 1 ? r1 : r2;
    const int* cc = m == 0 ? c0 : m == 1 ? c1 : c2;
    const float* vv = m == 0 ? v0 : m == 1 ? v1 : v2;
    int gr = rr[i] + m * N;
    int pos = atomicAdd(&hist[gr >> CSH], 1);  // LDS
    stage[pos] = make_int2((cc[i] << CSH) | (gr & ((1 << CSH) - 1)),
                           __float_as_int(vv[i]));
  }
}

// phase 2: one block per coarse bucket; LDS cursors for its 1024 rows; scatter
// the bucket's staging region into final CSR positions (262 KB window).
__global__ __launch_bounds__(TPB2) void csr_place2_kernel(
    const int* __restrict__ P, const int2* __restrict__ stage,
    int2* __restrict__ pairs, int M) {
  __shared__ int lcur[1 << CSH];
  int row0 = blockIdx.x << CSH;
  int row1 = row0 + (1 << CSH);
  if (row1 > M) row1 = M;
  for (int r = row0 + (int)threadIdx.x; r < row1; r += TPB2)
    lcur[r - row0] = P[r];
  __syncthreads();
  int start = P[row0], end = P[row1];
  for (int j = start + (int)threadIdx.x; j < end; j += TPB2) {
    int2 s = stage[j];
    int rl = s.x & ((1 << CSH) - 1);
    int col = ((unsigned)s.x) >> CSH;
    int pos = atomicAdd(&lcur[rl], 1);
    pairs[pos] = make_int2(col, s.y);
  }
}

// ---------------- dense GEMM: C[nrows,128] = A @ W (+bias) ----------------
// block 256 thr, tile 128 rows x 128 cols, thread 8x8.
// W staged in 32 KB LDS chunks (k-depth 64).
// Column split {cg*4, 64+cg*4}: 16 lanes sweep all 32 banks -> 2-way LDS
// aliasing (free per m136).
// NOTE: do NOT unroll the k4 loop — unrolling hoists 8 iterations of a[8]
// float4 A-loads, VGPR 256 + spill traffic.

__global__ __launch_bounds__(TPB) void gemm128_kernel(
    const float* __restrict__ A, const float* __restrict__ W,
    const float* __restrict__ bias, float* __restrict__ C, int nrows) {
  __shared__ float sW[64 * 128];
  const int cg = threadIdx.x & 15;
  const int rg = threadIdx.x >> 4;
  const int cA = cg * 4, cB = 64 + cg * 4;
  const int row0 = blockIdx.x * 128 + rg * 8;
  float acc[8][8];
#pragma unroll
  for (int j = 0; j < 8; ++j)
#pragma unroll
    for (int i = 0; i < 8; ++i) acc[j][i] = 0.f;

#pragma unroll 1
  for (int kc = 0; kc < 128; kc += 64) {
    for (int i = threadIdx.x * 4; i < 64 * 128; i += TPB * 4)
      *(float4*)&sW[i] = *(const float4*)&W[kc * 128 + i];
    __syncthreads();
#pragma unroll 1
    for (int k4 = 0; k4 < 64; k4 += 4) {
      float4 a[8];
#pragma unroll
      for (int j = 0; j < 8; ++j) {
        int r = row0 + j;
        a[j] = (r < nrows) ? *(const float4*)&A[(size_t)r * 128 + kc + k4]
                           : make_float4(0.f, 0.f, 0.f, 0.f);
      }
#pragma unroll
      for (int kk = 0; kk < 4; ++kk) {
        float4 w0 = *(const float4*)&sW[(k4 + kk) * 128 + cA];
        float4 w1 = *(const float4*)&sW[(k4 + kk) * 128 + cB];
#pragma unroll
        for (int j = 0; j < 8; ++j) {
          float aj = (kk == 0) ? a[j].x : (kk == 1) ? a[j].y : (kk == 2) ? a[j].z : a[j].w;
          acc[j][0] = fmaf(aj, w0.x, acc[j][0]);
          acc[j][1] = fmaf(aj, w0.y, acc[j][1]);
          acc[j][2] = fmaf(aj, w0.z, acc[j][2]);
          acc[j][3] = fmaf(aj, w0.w, acc[j][3]);
          acc[j][4] = fmaf(aj, w1.x, acc[j][4]);
          acc[j][5] = fmaf(aj, w1.y, acc[j][5]);
          acc[j][6] = fmaf(aj, w1.z, acc[j][6]);
          acc[j][7] = fmaf(aj, w1.w, acc[j][7]);
        }
      }
    }
    __syncthreads();
  }
  float bv[8];
  if (bias) {
    *(float4*)&bv[0] = *(const float4*)&bias[cA];
    *(float4*)&bv[4] = *(const float4*)&bias[cB];
  } else {
#pragma unroll
    for (int i = 0; i < 8; ++i) bv[i] = 0.f;
  }
#pragma unroll
  for (int j = 0; j < 8; ++j) {
    int r = row0 + j;
    if (r < nrows) {
      *(float4*)&C[(size_t)r * 128 + cA] =
          make_float4(acc[j][0] + bv[0], acc[j][1] + bv[1], acc[j][2] + bv[2], acc[j][3] + bv[3]);
      *(float4*)&C[(size_t)r * 128 + cB] =
          make_float4(acc[j][4] + bv[4], acc[j][5] + bv[5], acc[j][6] + bv[6], acc[j][7] + bv[7]);
    }
  }
}

// ---------------- fusion: score[v][n] = w2 . tanh(x[v,n,:] @ W1 + b1) ----------------

__global__ __launch_bounds__(TPB) void fusion_score_kernel(
    const float* __restrict__ x, const float* __restrict__ W1,
    const float* __restrict__ b1, const float* __restrict__ w2,
    float* __restrict__ score, int nrows) {
  __shared__ float sW[64 * 128];
  const int v = blockIdx.y;
  const float* A = x + (size_t)v * nrows * 128;
  const int cg = threadIdx.x & 15;
  const int rg = threadIdx.x >> 4;
  const int cA = cg * 4, cB = 64 + cg * 4;
  const int row0 = blockIdx.x * 128 + rg * 8;
  float acc[8][8];
#pragma unroll
  for (int j = 0; j < 8; ++j)
#pragma unroll
    for (int i = 0; i < 8; ++i) acc[j][i] = 0.f;

#pragma unroll 1
  for (int kc = 0; kc < 128; kc += 64) {
    for (int i = threadIdx.x * 4; i < 64 * 128; i += TPB * 4)
      *(float4*)&sW[i] = *(const float4*)&W1[kc * 128 + i];
    __syncthreads();
#pragma unroll 1
    for (int k4 = 0; k4 < 64; k4 += 4) {
      float4 a[8];
#pragma unroll
      for (int j = 0; j < 8; ++j) {
        int r = row0 + j;
        a[j] = (r < nrows) ? *(const float4*)&A[(size_t)r * 128 + kc + k4]
                           : make_float4(0.f, 0.f, 0.f, 0.f);
      }
#pragma unroll
      for (int kk = 0; kk < 4; ++kk) {
        float4 w0 = *(const float4*)&sW[(k4 + kk) * 128 + cA];
        float4 w1 = *(const float4*)&sW[(k4 + kk) * 128 + cB];
#pragma unroll
        for (int j = 0; j < 8; ++j) {
          float aj = (kk == 0) ? a[j].x : (kk == 1) ? a[j].y : (kk == 2) ? a[j].z : a[j].w;
          acc[j][0] = fmaf(aj, w0.x, acc[j][0]);
          acc[j][1] = fmaf(aj, w0.y, acc[j][1]);
          acc[j][2] = fmaf(aj, w0.z, acc[j][2]);
          acc[j][3] = fmaf(aj, w0.w, acc[j][3]);
          acc[j][4] = fmaf(aj, w1.x, acc[j][4]);
          acc[j][5] = fmaf(aj, w1.y, acc[j][5]);
          acc[j][6] = fmaf(aj, w1.z, acc[j][6]);
          acc[j][7] = fmaf(aj, w1.w, acc[j][7]);
        }
      }
    }
    __syncthreads();
  }
  float bb[8], ww[8];
  *(float4*)&bb[0] = *(const float4*)&b1[cA];
  *(float4*)&bb[4] = *(const float4*)&b1[cB];
  *(float4*)&ww[0] = *(const float4*)&w2[cA];
  *(float4*)&ww[4] = *(const float4*)&w2[cB];
#pragma unroll
  for (int j = 0; j < 8; ++j) {
    float p = 0.f;
#pragma unroll
    for (int i = 0; i < 8; ++i) p += tanhf(acc[j][i] + bb[i]) * ww[i];
#pragma unroll
    for (int off = 8; off > 0; off >>= 1) p += __shfl_down(p, off, 16);
    if (cg == 0 && row0 + j < nrows) score[(size_t)v * nrows + row0 + j] = p;
  }
}

// softmax over 2 views + weighted sum (b2 cancels in the 2-way softmax)
__global__ void combine_kernel(const float* __restrict__ x, const float* __restrict__ score,
                               float* __restrict__ fused, int nrows) {
  int i = blockIdx.x * TPB + threadIdx.x;  // over nrows*32 float4s
  if (i >= nrows * 32) return;
  int n = i >> 5;
  float s0 = score[n], s1 = score[nrows + n];
  float m = fmaxf(s0, s1);
  float e0 = expf(s0 - m), e1 = expf(s1 - m);
  float inv = 1.f / (e0 + e1);
  float w0 = e0 * inv, w1 = e1 * inv;
  float4 a = ((const float4*)x)[i];
  float4 b = ((const float4*)x)[(size_t)nrows * 32 + i];
  ((float4*)fused)[i] = make_float4(w0 * a.x + w1 * b.x, w0 * a.y + w1 * b.y,
                                    w0 * a.z + w1 * b.z, w0 * a.w + w1 * b.w);
}

// ---------------- spmm: y[r,:] = (relu?) sum val * x[col,:] (+add0 +add1) ----------------
// one 32-lane half-wave per row; lanes hold float4 (128 cols / 32 lanes).

__global__ __launch_bounds__(TPB) void spmm_kernel(
    const int* __restrict__ ptr, const int2* __restrict__ pairs,
    const float* __restrict__ x, float* __restrict__ y, int nrows, int do_relu,
    const float* __restrict__ add0, const float* __restrict__ add1) {
  int row = (blockIdx.x * TPB + threadIdx.x) >> 5;
  int hl = threadIdx.x & 31;
  if (row >= nrows) return;
  int start = ptr[row], end = ptr[row + 1];
  float ax = 0.f, ay = 0.f, az = 0.f, aw = 0.f;
  for (int j = start; j < end; j += 32) {
    int nrem = end - j;
    if (nrem > 32) nrem = 32;
    int2 pr = make_int2(0, 0);
    if (hl < nrem) pr = pairs[j + hl];
    for (int t = 0; t < nrem; ++t) {
      int c = __shfl(pr.x, t, 32);
      float v = __int_as_float(__shfl(pr.y, t, 32));
      const float4 xv = *(const float4*)&x[(size_t)c * 128 + hl * 4];
      ax = fmaf(v, xv.x, ax);
      ay = fmaf(v, xv.y, ay);
      az = fmaf(v, xv.z, az);
      aw = fmaf(v, xv.w, aw);
    }
  }
  if (do_relu) {
    ax = fmaxf(ax, 0.f); ay = fmaxf(ay, 0.f);
    az = fmaxf(az, 0.f); aw = fmaxf(aw, 0.f);
  }
  size_t o = (size_t)row * 128 + hl * 4;
  if (add0) { float4 t = *(const float4*)&add0[o]; ax += t.x; ay += t.y; az += t.z; aw += t.w; }
  if (add1) { float4 t = *(const float4*)&add1[o]; ax += t.x; ay += t.y; az += t.z; aw += t.w; }
  *(float4*)&y[o] = make_float4(ax, ay, az, aw);
}

// ---------------- launch ----------------

extern "C" void kernel_launch(void* const* d_in, const int* in_sizes, int n_in,
                              void* d_out, int out_size, void* d_ws, size_t ws_size,
                              hipStream_t stream) {
  const float* x   = (const float*)d_in[0];
  const float* fw1 = (const float*)d_in[1];
  const float* fb1 = (const float*)d_in[2];
  const float* fw2 = (const float*)d_in[3];
  // d_in[4] = fusion_b2: cancels in 2-way softmax
  const float* hgw = (const float*)d_in[5];
  const float* lgw = (const float*)d_in[6];
  const float* lgb = (const float*)d_in[7];
  const float* c1v = (const float*)d_in[8];
  const float* c2v = (const float*)d_in[9];
  const float* lgv = (const float*)d_in[10];
  const int* c1r = (const int*)d_in[11];
  const int* c1c = (const int*)d_in[12];
  const int* c2r = (const int*)d_in[13];
  const int* c2c = (const int*)d_in[14];
  const int* lgr = (const int*)d_in[15];
  const int* lgc = (const int*)d_in[16];

  const int N = in_sizes[0] / 256;  // x is [2,N,128]
  const int E = in_sizes[8];
  const int M = 3 * N;
  const int C = (M + (1 << CSH) - 1) >> CSH;  // coarse buckets (293 for N=100K)

  char* ws = (char*)d_ws;
  size_t off = 0;
  auto alloc = [&](size_t bytes) -> void* {
    void* p = ws + off;
    off += (bytes + 511) & ~(size_t)511;
    return p;
  };
  int* P      = (int*)alloc((size_t)(M + 1) * 4);
  int* S      = (int*)alloc((size_t)4096 * 4);
  int* counts = (int*)alloc((size_t)M * 4);
  int* ccur   = (int*)alloc((size_t)(C + 1) * 4);
  int2* pairs = (int2*)alloc((size_t)3 * E * 8);
  float* score = (float*)alloc((size_t)2 * N * 4);
  float* Fbase = (float*)alloc((size_t)3 * N * 128 * 4);
  float* F0 = Fbase;
  float* F1 = Fbase + (size_t)N * 128;
  float* F2 = Fbase + (size_t)2 * N * 128;
  // CSR-build staging aliases the F buffers: the build completes (stream-
  // ordered) before fusion/combine first write F0/F1/F2.
  // stage: 3E*8 = 76.8 MB <= F region 153.6 MB.
  int2* stage = (int2*)Fbase;
  float* outH = (float*)d_out;
  float* outA = (float*)d_out + (size_t)N * 128;

  // ---- CSR build for [coef1 | coef2 | lg] concatenated ----
  hipMemsetAsync(counts, 0, (size_t)M * 4, stream);
  int gE = (E + TPB - 1) / TPB;
  dim3 g3(gE, 3);
  hist3_kernel<<<g3, TPB, 0, stream>>>(c1r, c2r, lgr, E, N, counts);
  int NB = (M + 2047) / 2048;
  scan1_kernel<<<NB, TPB, 0, stream>>>(counts, M, P, S);
  scan2_kernel<<<1, TPB, 0, stream>>>(S, NB);
  scan3_kernel<<<NB, TPB, 0, stream>>>(P, S, M);
  ccur_init_kernel<<<(C + TPB - 1) / TPB, TPB, 0, stream>>>(P, ccur, C, M);
  int NBS = (3 * E + CHUNK - 1) / CHUNK;
  binsort_kernel<<<NBS, TPB, 0, stream>>>(c1r, c1c, c1v, c2r, c2c, c2v,
                                          lgr, lgc, lgv, E, N, C, ccur, stage);
  csr_place2_kernel<<<C, TPB2, 0, stream>>>(P, stage, pairs, M);

  // ---- fusion ----
  dim3 gf((N + 127) / 128, 2);
  fusion_score_kernel<<<gf, TPB, 0, stream>>>(x, fw1, fb1, fw2, score, N);
  combine_kernel<<<(N * 32 + TPB - 1) / TPB, TPB, 0, stream>>>(x, score, F0, N);

  int gg = (N + 127) / 128;
  int gs = (N + 7) / 8;  // spmm: 8 half-waves/block, half-wave per row

  // ---- HGCN ----
  gemm128_kernel<<<gg, TPB, 0, stream>>>(F0, hgw + 0 * 16384, nullptr, F1, N);
  spmm_kernel<<<gs, TPB, 0, stream>>>(P, pairs, F1, F2, N, 1, nullptr, nullptr);      // h1
  gemm128_kernel<<<gg, TPB, 0, stream>>>(F2, hgw + 1 * 16384, nullptr, F1, N);
  spmm_kernel<<<gs, TPB, 0, stream>>>(P, pairs, F1, F2, N, 1, nullptr, nullptr);      // h2
  gemm128_kernel<<<gg, TPB, 0, stream>>>(F2, hgw + 2 * 16384, nullptr, F1, N);
  spmm_kernel<<<gs, TPB, 0, stream>>>(P, pairs, F1, outH, N, 1, nullptr, nullptr);    // h3 -> out[0:N]
  spmm_kernel<<<gs, TPB, 0, stream>>>(P + N, pairs, outH, F0, N, 1, nullptr, nullptr); // y

  // ---- LineConv ----
  gemm128_kernel<<<gg, TPB, 0, stream>>>(F0, lgw + 0 * 16384, lgb + 0, F1, N);
  spmm_kernel<<<gs, TPB, 0, stream>>>(P + 2 * N, pairs, F1, F2, N, 0, nullptr, nullptr); // cur1
  gemm128_kernel<<<gg, TPB, 0, stream>>>(F2, lgw + 1 * 16384, lgb + 128, F1, N);
  // cur2 + y + cur1 -> out[N:2N]
  spmm_kernel<<<gs, TPB, 0, stream>>>(P + 2 * N, pairs, F1, outA, N, 0, F0, F2);
}

// Round 4
// 2625.902 us; speedup vs baseline: 1.5105x; 1.1421x over previous
//
#include <hip/hip_runtime.h>
#include <cmath>

#define TPB 256
#define CSH 10               // coarse bucket = 1024 rows
#define CMAX 512             // max coarse buckets supported by LDS hist (M <= 512*1024)
#define CHUNK 16384          // edges per binsort/count block
#define TPB2 1024            // threads for csr_place3 / scanC

// ---------------- CSR build ----------------
// R1/R2 post-mortem: scattered single-edge global appends are write-amplified
// ~6-7x (every 64B line's writes arrive from different blocks over the whole
// kernel -> no L2 line survives). Write-combining needs TEMPORAL clustering.
// R3 post-mortem: hist3's 9.6M device-scope atomics to a shared 1.2MB counts
// array cost ~32B write-through EACH (299MB measured) -- cross-XCD atomics
// are memory-side transactions. Fix: never do per-element global atomics.
//   1) coarse_count: LDS hist per 16K-edge chunk -> one bulk atomic per
//      (block, coarse bucket) (~172K atomics total).
//   2) scanC: 293-entry scan -> coarse offsets Pc (one tiny block).
//   3) binsort: block-local counting sort; bulk reservation from ccur (=Pc);
//      contiguous ~448B runs written within the block's lifetime (~1.1x amp).
//   4) csr_place3: one block per coarse bucket derives per-row structure
//      LOCALLY (LDS hist of row-low-10 + LDS scan), writes the global P slice,
//      then scatters into final CSR order inside a 262KB window.
// The entire M-sized histogram + scan machinery is gone.

// phase 0: coarse histogram. LDS-aggregated; ~586 global atomics per counter.
__global__ __launch_bounds__(TPB) void coarse_count_kernel(
    const int* __restrict__ r0, const int* __restrict__ r1,
    const int* __restrict__ r2, int E, int N, int C, int* __restrict__ Cc) {
  __shared__ int hist[CMAX];
  int tot = 3 * E;
  int t0 = blockIdx.x * CHUNK;
  int t1 = t0 + CHUNK;
  if (t1 > tot) t1 = tot;
  for (int c = threadIdx.x; c < C; c += TPB) hist[c] = 0;
  __syncthreads();
  for (int t = t0 + (int)threadIdx.x; t < t1; t += TPB) {
    int m = (t >= 2 * E) ? 2 : (t >= E) ? 1 : 0;
    int i = t - m * E;
    const int* rr = m == 0 ? r0 : m == 1 ? r1 : r2;
    atomicAdd(&hist[(rr[i] + m * N) >> CSH], 1);
  }
  __syncthreads();
  for (int c = threadIdx.x; c < C; c += TPB) {
    int h = hist[c];
    if (h) atomicAdd(&Cc[c], h);
  }
}

// phase 0b: exclusive scan of the C coarse counts (C <= 1024). Pc[0..C]; ccur=Pc.
__global__ __launch_bounds__(TPB2) void scanC_kernel(
    const int* __restrict__ Cc, int* __restrict__ Pc, int* __restrict__ ccur, int C) {
  __shared__ int lds[TPB2];
  int tid = threadIdx.x;
  int v = (tid < C) ? Cc[tid] : 0;
  lds[tid] = v;
  __syncthreads();
  for (int off = 1; off < TPB2; off <<= 1) {
    int t = (tid >= off) ? lds[tid - off] : 0;
    __syncthreads();
    if (tid >= off) lds[tid] += t;
    __syncthreads();
  }
  int incl = lds[tid];
  int excl = incl - v;
  if (tid < C) { Pc[tid] = excl; ccur[tid] = excl; }
  if (tid == C - 1) Pc[C] = incl;
}

// phase 1: block-local counting sort into coarse-bucket staging runs.
// Record: (col<<CSH | row_low_bits, val) -- 8 B. Requires col < 2^(31-CSH)
// (N=100K << 2^21, ok).
__global__ __launch_bounds__(TPB) void binsort_kernel(
    const int* __restrict__ r0, const int* __restrict__ c0, const float* __restrict__ v0,
    const int* __restrict__ r1, const int* __restrict__ c1, const float* __restrict__ v1,
    const int* __restrict__ r2, const int* __restrict__ c2, const float* __restrict__ v2,
    int E, int N, int C, int* __restrict__ ccur, int2* __restrict__ stage) {
  __shared__ int hist[CMAX];
  int t0 = blockIdx.x * CHUNK;
  int t1 = t0 + CHUNK;
  int tot = 3 * E;
  if (t1 > tot) t1 = tot;
  for (int c = threadIdx.x; c < C; c += TPB) hist[c] = 0;
  __syncthreads();
  // pass A: LDS histogram of this chunk by coarse bucket
  for (int t = t0 + (int)threadIdx.x; t < t1; t += TPB) {
    int m = (t >= 2 * E) ? 2 : (t >= E) ? 1 : 0;
    int i = t - m * E;
    const int* rr = m == 0 ? r0 : m == 1 ? r1 : r2;
    int gr = rr[i] + m * N;
    atomicAdd(&hist[gr >> CSH], 1);
  }
  __syncthreads();
  // bulk reservation: one global atomic per non-empty bucket; hist becomes
  // the block's running cursor per bucket.
  for (int c = threadIdx.x; c < C; c += TPB) {
    int h = hist[c];
    hist[c] = h ? atomicAdd(&ccur[c], h) : 0;
  }
  __syncthreads();
  // pass B: re-read chunk (L2-hot) and stream into reserved runs
  for (int t = t0 + (int)threadIdx.x; t < t1; t += TPB) {
    int m = (t >= 2 * E) ? 2 : (t >= E) ? 1 : 0;
    int i = t - m * E;
    const int* rr = m == 0 ? r0 : m == 1 ? r1 : r2;
    const int* cc = m == 0 ? c0 : m == 1 ? c1 : c2;
    const float* vv = m == 0 ? v0 : m == 1 ? v1 : v2;
    int gr = rr[i] + m * N;
    int pos = atomicAdd(&hist[gr >> CSH], 1);  // LDS
    stage[pos] = make_int2((cc[i] << CSH) | (gr & ((1 << CSH) - 1)),
                           __float_as_int(vv[i]));
  }
}

// phase 2: one block per coarse bucket. Derive per-row structure locally:
// LDS hist of row-low-10 bits -> LDS scan -> write global P slice -> scatter
// the bucket's staging region into final CSR positions (262 KB window).
__global__ __launch_bounds__(TPB2) void csr_place3_kernel(
    const int* __restrict__ Pc, const int2* __restrict__ stage,
    int2* __restrict__ pairs, int* __restrict__ P, int M, int C) {
  __shared__ int h[1 << CSH];
  const int tid = threadIdx.x;
  const int row0 = blockIdx.x << CSH;
  const int start = Pc[blockIdx.x], end = Pc[blockIdx.x + 1];
  h[tid] = 0;
  __syncthreads();
  for (int j = start + tid; j < end; j += TPB2)
    atomicAdd(&h[stage[j].x & ((1 << CSH) - 1)], 1);
  __syncthreads();
  int cnt = h[tid];
  for (int off = 1; off < TPB2; off <<= 1) {  // inclusive Hillis-Steele
    int t = (tid >= off) ? h[tid - off] : 0;
    __syncthreads();
    if (tid >= off) h[tid] += t;
    __syncthreads();
  }
  int cur = start + (h[tid] - cnt);  // start + exclusive prefix
  int row = row0 + tid;
  if (row < M) P[row] = cur;
  if (blockIdx.x == C - 1 && tid == 0) P[M] = end;
  h[tid] = cur;  // own-slot rewrite; no cross-thread read until next sync
  __syncthreads();
  for (int j = start + tid; j < end; j += TPB2) {
    int2 s = stage[j];
    int rl = s.x & ((1 << CSH) - 1);
    int pos = atomicAdd(&h[rl], 1);
    pairs[pos] = make_int2(((unsigned)s.x) >> CSH, s.y);
  }
}

// ---------------- dense GEMM: C[nrows,128] = A @ W (+bias) ----------------
// block 256 thr, tile 128 rows x 128 cols, thread 8x8.
// W staged in 32 KB LDS chunks (k-depth 64).
// Column split {cg*4, 64+cg*4}: 16 lanes sweep all 32 banks -> 2-way LDS
// aliasing (free per m136).
// NOTE: do NOT unroll the k4 loop — unrolling hoists 8 iterations of a[8]
// float4 A-loads, VGPR 256 + spill traffic.

__global__ __launch_bounds__(TPB) void gemm128_kernel(
    const float* __restrict__ A, const float* __restrict__ W,
    const float* __restrict__ bias, float* __restrict__ C, int nrows) {
  __shared__ float sW[64 * 128];
  const int cg = threadIdx.x & 15;
  const int rg = threadIdx.x >> 4;
  const int cA = cg * 4, cB = 64 + cg * 4;
  const int row0 = blockIdx.x * 128 + rg * 8;
  float acc[8][8];
#pragma unroll
  for (int j = 0; j < 8; ++j)
#pragma unroll
    for (int i = 0; i < 8; ++i) acc[j][i] = 0.f;

#pragma unroll 1
  for (int kc = 0; kc < 128; kc += 64) {
    for (int i = threadIdx.x * 4; i < 64 * 128; i += TPB * 4)
      *(float4*)&sW[i] = *(const float4*)&W[kc * 128 + i];
    __syncthreads();
#pragma unroll 1
    for (int k4 = 0; k4 < 64; k4 += 4) {
      float4 a[8];
#pragma unroll
      for (int j = 0; j < 8; ++j) {
        int r = row0 + j;
        a[j] = (r < nrows) ? *(const float4*)&A[(size_t)r * 128 + kc + k4]
                           : make_float4(0.f, 0.f, 0.f, 0.f);
      }
#pragma unroll
      for (int kk = 0; kk < 4; ++kk) {
        float4 w0 = *(const float4*)&sW[(k4 + kk) * 128 + cA];
        float4 w1 = *(const float4*)&sW[(k4 + kk) * 128 + cB];
#pragma unroll
        for (int j = 0; j < 8; ++j) {
          float aj = (kk == 0) ? a[j].x : (kk == 1) ? a[j].y : (kk == 2) ? a[j].z : a[j].w;
          acc[j][0] = fmaf(aj, w0.x, acc[j][0]);
          acc[j][1] = fmaf(aj, w0.y, acc[j][1]);
          acc[j][2] = fmaf(aj, w0.z, acc[j][2]);
          acc[j][3] = fmaf(aj, w0.w, acc[j][3]);
          acc[j][4] = fmaf(aj, w1.x, acc[j][4]);
          acc[j][5] = fmaf(aj, w1.y, acc[j][5]);
          acc[j][6] = fmaf(aj, w1.z, acc[j][6]);
          acc[j][7] = fmaf(aj, w1.w, acc[j][7]);
        }
      }
    }
    __syncthreads();
  }
  float bv[8];
  if (bias) {
    *(float4*)&bv[0] = *(const float4*)&bias[cA];
    *(float4*)&bv[4] = *(const float4*)&bias[cB];
  } else {
#pragma unroll
    for (int i = 0; i < 8; ++i) bv[i] = 0.f;
  }
#pragma unroll
  for (int j = 0; j < 8; ++j) {
    int r = row0 + j;
    if (r < nrows) {
      *(float4*)&C[(size_t)r * 128 + cA] =
          make_float4(acc[j][0] + bv[0], acc[j][1] + bv[1], acc[j][2] + bv[2], acc[j][3] + bv[3]);
      *(float4*)&C[(size_t)r * 128 + cB] =
          make_float4(acc[j][4] + bv[4], acc[j][5] + bv[5], acc[j][6] + bv[6], acc[j][7] + bv[7]);
    }
  }
}

// ---------------- fusion: score[v][n] = w2 . tanh(x[v,n,:] @ W1 + b1) ----------------

__global__ __launch_bounds__(TPB) void fusion_score_kernel(
    const float* __restrict__ x, const float* __restrict__ W1,
    const float* __restrict__ b1, const float* __restrict__ w2,
    float* __restrict__ score, int nrows) {
  __shared__ float sW[64 * 128];
  const int v = blockIdx.y;
  const float* A = x + (size_t)v * nrows * 128;
  const int cg = threadIdx.x & 15;
  const int rg = threadIdx.x >> 4;
  const int cA = cg * 4, cB = 64 + cg * 4;
  const int row0 = blockIdx.x * 128 + rg * 8;
  float acc[8][8];
#pragma unroll
  for (int j = 0; j < 8; ++j)
#pragma unroll
    for (int i = 0; i < 8; ++i) acc[j][i] = 0.f;

#pragma unroll 1
  for (int kc = 0; kc < 128; kc += 64) {
    for (int i = threadIdx.x * 4; i < 64 * 128; i += TPB * 4)
      *(float4*)&sW[i] = *(const float4*)&W1[kc * 128 + i];
    __syncthreads();
#pragma unroll 1
    for (int k4 = 0; k4 < 64; k4 += 4) {
      float4 a[8];
#pragma unroll
      for (int j = 0; j < 8; ++j) {
        int r = row0 + j;
        a[j] = (r < nrows) ? *(const float4*)&A[(size_t)r * 128 + kc + k4]
                           : make_float4(0.f, 0.f, 0.f, 0.f);
      }
#pragma unroll
      for (int kk = 0; kk < 4; ++kk) {
        float4 w0 = *(const float4*)&sW[(k4 + kk) * 128 + cA];
        float4 w1 = *(const float4*)&sW[(k4 + kk) * 128 + cB];
#pragma unroll
        for (int j = 0; j < 8; ++j) {
          float aj = (kk == 0) ? a[j].x : (kk == 1) ? a[j].y : (kk == 2) ? a[j].z : a[j].w;
          acc[j][0] = fmaf(aj, w0.x, acc[j][0]);
          acc[j][1] = fmaf(aj, w0.y, acc[j][1]);
          acc[j][2] = fmaf(aj, w0.z, acc[j][2]);
          acc[j][3] = fmaf(aj, w0.w, acc[j][3]);
          acc[j][4] = fmaf(aj, w1.x, acc[j][4]);
          acc[j][5] = fmaf(aj, w1.y, acc[j][5]);
          acc[j][6] = fmaf(aj, w1.z, acc[j][6]);
          acc[j][7] = fmaf(aj, w1.w, acc[j][7]);
        }
      }
    }
    __syncthreads();
  }
  float bb[8], ww[8];
  *(float4*)&bb[0] = *(const float4*)&b1[cA];
  *(float4*)&bb[4] = *(const float4*)&b1[cB];
  *(float4*)&ww[0] = *(const float4*)&w2[cA];
  *(float4*)&ww[4] = *(const float4*)&w2[cB];
#pragma unroll
  for (int j = 0; j < 8; ++j) {
    float p = 0.f;
#pragma unroll
    for (int i = 0; i < 8; ++i) p += tanhf(acc[j][i] + bb[i]) * ww[i];
#pragma unroll
    for (int off = 8; off > 0; off >>= 1) p += __shfl_down(p, off, 16);
    if (cg == 0 && row0 + j < nrows) score[(size_t)v * nrows + row0 + j] = p;
  }
}

// softmax over 2 views + weighted sum (b2 cancels in the 2-way softmax)
__global__ void combine_kernel(const float* __restrict__ x, const float* __restrict__ score,
                               float* __restrict__ fused, int nrows) {
  int i = blockIdx.x * TPB + threadIdx.x;  // over nrows*32 float4s
  if (i >= nrows * 32) return;
  int n = i >> 5;
  float s0 = score[n], s1 = score[nrows + n];
  float m = fmaxf(s0, s1);
  float e0 = expf(s0 - m), e1 = expf(s1 - m);
  float inv = 1.f / (e0 + e1);
  float w0 = e0 * inv, w1 = e1 * inv;
  float4 a = ((const float4*)x)[i];
  float4 b = ((const float4*)x)[(size_t)nrows * 32 + i];
  ((float4*)fused)[i] = make_float4(w0 * a.x + w1 * b.x, w0 * a.y + w1 * b.y,
                                    w0 * a.z + w1 * b.z, w0 * a.w + w1 * b.w);
}

// ---------------- spmm: y[r,:] = (relu?) sum val * x[col,:] (+add0 +add1) ----------------
// one 32-lane half-wave per row; lanes hold float4 (128 cols / 32 lanes).

__global__ __launch_bounds__(TPB) void spmm_kernel(
    const int* __restrict__ ptr, const int2* __restrict__ pairs,
    const float* __restrict__ x, float* __restrict__ y, int nrows, int do_relu,
    const float* __restrict__ add0, const float* __restrict__ add1) {
  int row = (blockIdx.x * TPB + threadIdx.x) >> 5;
  int hl = threadIdx.x & 31;
  if (row >= nrows) return;
  int start = ptr[row], end = ptr[row + 1];
  float ax = 0.f, ay = 0.f, az = 0.f, aw = 0.f;
  for (int j = start; j < end; j += 32) {
    int nrem = end - j;
    if (nrem > 32) nrem = 32;
    int2 pr = make_int2(0, 0);
    if (hl < nrem) pr = pairs[j + hl];
    for (int t = 0; t < nrem; ++t) {
      int c = __shfl(pr.x, t, 32);
      float v = __int_as_float(__shfl(pr.y, t, 32));
      const float4 xv = *(const float4*)&x[(size_t)c * 128 + hl * 4];
      ax = fmaf(v, xv.x, ax);
      ay = fmaf(v, xv.y, ay);
      az = fmaf(v, xv.z, az);
      aw = fmaf(v, xv.w, aw);
    }
  }
  if (do_relu) {
    ax = fmaxf(ax, 0.f); ay = fmaxf(ay, 0.f);
    az = fmaxf(az, 0.f); aw = fmaxf(aw, 0.f);
  }
  size_t o = (size_t)row * 128 + hl * 4;
  if (add0) { float4 t = *(const float4*)&add0[o]; ax += t.x; ay += t.y; az += t.z; aw += t.w; }
  if (add1) { float4 t = *(const float4*)&add1[o]; ax += t.x; ay += t.y; az += t.z; aw += t.w; }
  *(float4*)&y[o] = make_float4(ax, ay, az, aw);
}

// ---------------- launch ----------------

extern "C" void kernel_launch(void* const* d_in, const int* in_sizes, int n_in,
                              void* d_out, int out_size, void* d_ws, size_t ws_size,
                              hipStream_t stream) {
  const float* x   = (const float*)d_in[0];
  const float* fw1 = (const float*)d_in[1];
  const float* fb1 = (const float*)d_in[2];
  const float* fw2 = (const float*)d_in[3];
  // d_in[4] = fusion_b2: cancels in 2-way softmax
  const float* hgw = (const float*)d_in[5];
  const float* lgw = (const float*)d_in[6];
  const float* lgb = (const float*)d_in[7];
  const float* c1v = (const float*)d_in[8];
  const float* c2v = (const float*)d_in[9];
  const float* lgv = (const float*)d_in[10];
  const int* c1r = (const int*)d_in[11];
  const int* c1c = (const int*)d_in[12];
  const int* c2r = (const int*)d_in[13];
  const int* c2c = (const int*)d_in[14];
  const int* lgr = (const int*)d_in[15];
  const int* lgc = (const int*)d_in[16];

  const int N = in_sizes[0] / 256;  // x is [2,N,128]
  const int E = in_sizes[8];
  const int M = 3 * N;
  const int C = (M + (1 << CSH) - 1) >> CSH;  // coarse buckets (293 for N=100K)

  char* ws = (char*)d_ws;
  size_t off = 0;
  auto alloc = [&](size_t bytes) -> void* {
    void* p = ws + off;
    off += (bytes + 511) & ~(size_t)511;
    return p;
  };
  int* P      = (int*)alloc((size_t)(M + 1) * 4);
  int* Cc     = (int*)alloc((size_t)(C + 1) * 4);
  int* Pc     = (int*)alloc((size_t)(C + 1) * 4);
  int* ccur   = (int*)alloc((size_t)(C + 1) * 4);
  int2* pairs = (int2*)alloc((size_t)3 * E * 8);
  float* score = (float*)alloc((size_t)2 * N * 4);
  float* Fbase = (float*)alloc((size_t)3 * N * 128 * 4);
  float* F0 = Fbase;
  float* F1 = Fbase + (size_t)N * 128;
  float* F2 = Fbase + (size_t)2 * N * 128;
  // CSR-build staging aliases the F buffers: the build completes (stream-
  // ordered) before fusion/combine first write F0/F1/F2.
  // stage: 3E*8 = 76.8 MB <= F region 153.6 MB.
  int2* stage = (int2*)Fbase;
  float* outH = (float*)d_out;
  float* outA = (float*)d_out + (size_t)N * 128;

  // ---- CSR build for [coef1 | coef2 | lg] concatenated ----
  hipMemsetAsync(Cc, 0, (size_t)(C + 1) * 4, stream);
  int NBS = (3 * E + CHUNK - 1) / CHUNK;
  coarse_count_kernel<<<NBS, TPB, 0, stream>>>(c1r, c2r, lgr, E, N, C, Cc);
  scanC_kernel<<<1, TPB2, 0, stream>>>(Cc, Pc, ccur, C);
  binsort_kernel<<<NBS, TPB, 0, stream>>>(c1r, c1c, c1v, c2r, c2c, c2v,
                                          lgr, lgc, lgv, E, N, C, ccur, stage);
  csr_place3_kernel<<<C, TPB2, 0, stream>>>(Pc, stage, pairs, P, M, C);

  // ---- fusion ----
  dim3 gf((N + 127) / 128, 2);
  fusion_score_kernel<<<gf, TPB, 0, stream>>>(x, fw1, fb1, fw2, score, N);
  combine_kernel<<<(N * 32 + TPB - 1) / TPB, TPB, 0, stream>>>(x, score, F0, N);

  int gg = (N + 127) / 128;
  int gs = (N + 7) / 8;  // spmm: 8 half-waves/block, half-wave per row

  // ---- HGCN ----
  gemm128_kernel<<<gg, TPB, 0, stream>>>(F0, hgw + 0 * 16384, nullptr, F1, N);
  spmm_kernel<<<gs, TPB, 0, stream>>>(P, pairs, F1, F2, N, 1, nullptr, nullptr);      // h1
  gemm128_kernel<<<gg, TPB, 0, stream>>>(F2, hgw + 1 * 16384, nullptr, F1, N);
  spmm_kernel<<<gs, TPB, 0, stream>>>(P, pairs, F1, F2, N, 1, nullptr, nullptr);      // h2
  gemm128_kernel<<<gg, TPB, 0, stream>>>(F2, hgw + 2 * 16384, nullptr, F1, N);
  spmm_kernel<<<gs, TPB, 0, stream>>>(P, pairs, F1, outH, N, 1, nullptr, nullptr);    // h3 -> out[0:N]
  spmm_kernel<<<gs, TPB, 0, stream>>>(P + N, pairs, outH, F0, N, 1, nullptr, nullptr); // y

  // ---- LineConv ----
  gemm128_kernel<<<gg, TPB, 0, stream>>>(F0, lgw + 0 * 16384, lgb + 0, F1, N);
  spmm_kernel<<<gs, TPB, 0, stream>>>(P + 2 * N, pairs, F1, F2, N, 0, nullptr, nullptr); // cur1
  gemm128_kernel<<<gg, TPB, 0, stream>>>(F2, lgw + 1 * 16384, lgb + 128, F1, N);
  // cur2 + y + cur1 -> out[N:2N]
  spmm_kernel<<<gs, TPB, 0, stream>>>(P + 2 * N, pairs, F1, outA, N, 0, F0, F2);
}